// Round 20
// baseline (170.330 us; speedup 1.0000x reference)
//
#include <hip/hip_runtime.h>
#include <hip/hip_fp16.h>
#include <math.h>

#define NN 100000
#define NE 1600000
#define RR 5
#define HH 64
#define KK 10000
#define NBB 2
#define NBK 391            // dst buckets of 256 nodes
#define EPB 6250           // edges per block in bucket pass (256 blocks)
#define BSLOT 4608         // padded slots per bucket (mean 4096 + 8 sigma)
#define MPITCH 136         // LDS mix row pitch in halves
#define NWT (2 * 64 * 192) // Wt element count
#define NIB 6250           // init main blocks (NN*16/256)
#define NWB 96             // Wt blocks (NWT/256)
#define PEBLK ((KK * 16 + 255) / 256)   // PE blocks (tail of K2)

typedef _Float16 f16x8 __attribute__((ext_vector_type(8)));
typedef float f32x4 __attribute__((ext_vector_type(4)));

// ---------------- K1: init hH + Wt build + bucket place (disjoint block ranges) ----------------
// blocks [0,NIB): hH[n]=fp16(emb[x[n]]), absorbed=0
// blocks [NIB,NIB+NWB): Wt
// blocks [NIB+NWB, NIB+NWB+256): bplace main (bcur pre-zeroed by memset)
__launch_bounds__(256)
__global__ void k_init_place(const int* __restrict__ x, const float4* __restrict__ emb4,
                             unsigned short* __restrict__ hH, int* __restrict__ absorbed,
                             const float* __restrict__ b0, const float* __restrict__ r0,
                             const float* __restrict__ b1, const float* __restrict__ r1,
                             unsigned short* __restrict__ Wt,
                             const int* __restrict__ src, const int* __restrict__ dst,
                             const int* __restrict__ et, int* __restrict__ bcur,
                             unsigned int* __restrict__ ebuf) {
    __shared__ unsigned int ent[EPB];
    __shared__ unsigned short bkt[EPB];
    __shared__ int hist[NBK];
    __shared__ int lbase[NBK];
    __shared__ int lcur[NBK];
    int tid = threadIdx.x;
    int blk = blockIdx.x;

    if (blk < NIB) {
        int idx = blk * 256 + tid;
        int n = idx >> 4;
        int q = idx & 15;
        float4 v = emb4[x[n] * 16 + q];
        __half2 lo = __floats2half2_rn(v.x, v.y);
        __half2 hi = __floats2half2_rn(v.z, v.w);
        *(uint2*)&hH[(size_t)n * HH + q * 4] = make_uint2(*(unsigned*)&lo, *(unsigned*)&hi);
        if (idx < NN) absorbed[idx] = 0;
        return;
    }
    if (blk < NIB + NWB) {
        int widx = (blk - NIB) * 256 + tid;
        int layer = widx / (64 * 192);
        int rem = widx - layer * 64 * 192;
        int o = rem / 192, k = rem - o * 192;
        const float* bases = layer ? b1 : b0;
        const float* root  = layer ? r1 : r0;
        float w = (k < 64)  ? bases[(size_t)k * HH + o]
                : (k < 128) ? bases[(size_t)HH * HH + (size_t)(k - 64) * HH + o]
                            : root[(size_t)(k - 128) * HH + o];
        __half hv = __float2half_rn(w);
        Wt[widx] = *(unsigned short*)&hv;
        return;
    }

    // ---- bplace main ----
    int pb = blk - (NIB + NWB);
    for (int i = tid; i < NBK; i += 256) { hist[i] = 0; lcur[i] = 0; }
    __syncthreads();
    int e0 = pb * EPB;
    int e1 = e0 + EPB < NE ? e0 + EPB : NE;
    int cnt = e1 - e0;
    for (int i = tid; i < cnt; i += 256) {
        int e = e0 + i;
        int d = dst[e];
        int b = d >> 8;
        ent[i] = ((unsigned)(d & 255) << 20) | ((unsigned)src[e] << 3) | (unsigned)et[e];
        bkt[i] = (unsigned short)b;
        atomicAdd(&hist[b], 1);
    }
    __syncthreads();
    for (int i = tid; i < NBK; i += 256)
        if (hist[i]) lbase[i] = i * BSLOT + atomicAdd(&bcur[i], hist[i]);
    __syncthreads();
    for (int i = tid; i < cnt; i += 256) {
        int b = bkt[i];
        int r = atomicAdd(&lcur[b], 1);
        int idx = lbase[b] + r;
        if (idx < (b + 1) * BSLOT)
            ebuf[idx] = ent[i];
    }
}

// ---------------- K2: bucket sort (blocks [0,NBK)) + PE add (tail blocks) ----------------
// epair entry = cnt<<23 | src<<3 | rel
__launch_bounds__(256)
__global__ void k_bsort(const unsigned int* __restrict__ ebuf, const int* __restrict__ bcur,
                        unsigned int* __restrict__ epair, int2* __restrict__ rowse,
                        float* __restrict__ norm5g,
                        const int* __restrict__ order, unsigned short* __restrict__ hH,
                        int* __restrict__ absorbed) {
    __shared__ unsigned int el[BSLOT];
    __shared__ int cnt5[256 * RR];
    __shared__ int dcur[256];
    __shared__ int s[256];
    int tid = threadIdx.x;

    if (blockIdx.x >= NBK) {
        // ---- PE add + absorbed mask ----
        int idx = (blockIdx.x - NBK) * 256 + tid;
        if (idx >= KK * 16) return;
        int t = idx >> 4;
        int q = idx & 15;
        int node = order[t];
        float v = (float)sin((double)(t + 1));   // exact arg reduction, matches np
        uint2 u = *(uint2*)&hH[(size_t)node * HH + q * 4];
        float2 lo = __half22float2(*(__half2*)&u.x);
        float2 hi = __half22float2(*(__half2*)&u.y);
        __half2 nlo = __floats2half2_rn(lo.x + v, lo.y + v);
        __half2 nhi = __floats2half2_rn(hi.x + v, hi.y + v);
        *(uint2*)&hH[(size_t)node * HH + q * 4] = make_uint2(*(unsigned*)&nlo, *(unsigned*)&nhi);
        if (q == 0) absorbed[node] = 1;
        return;
    }

    int b = blockIdx.x;
    int base = b * BSLOT;
    int sz = bcur[b];
    if (sz > BSLOT) sz = BSLOT;

    for (int i = tid; i < sz; i += 256) el[i] = ebuf[base + i];
    for (int i = tid; i < 256 * RR; i += 256) cnt5[i] = 0;
    __syncthreads();
    for (int i = tid; i < sz; i += 256) {
        unsigned int e = el[i];
        atomicAdd(&cnt5[(e >> 20) * RR + (e & 7)], 1);
    }
    __syncthreads();
    int deg = 0;
#pragma unroll
    for (int r = 0; r < RR; r++) deg += cnt5[tid * RR + r];
    s[tid] = deg;
    dcur[tid] = 0;
    __syncthreads();
#pragma unroll
    for (int off = 1; off < 256; off <<= 1) {
        int t = (tid >= off) ? s[tid - off] : 0;
        __syncthreads();
        s[tid] += t;
        __syncthreads();
    }
    int rs = s[tid] - deg;      // exclusive within bucket
    int d = b * 256 + tid;
    if (d < NN) {
        rowse[d] = make_int2(base + rs, base + rs + deg);
#pragma unroll
        for (int r = 0; r < RR; r++) {
            int c = cnt5[tid * RR + r];
            norm5g[(size_t)d * RR + r] = 1.0f / (float)(c > 1 ? c : 1);
        }
    }
    __syncthreads();
    for (int i = tid; i < sz; i += 256) {
        unsigned int e = el[i];
        int d8 = e >> 20;
        int rk = atomicAdd(&dcur[d8], 1);
        int pos = base + (s[d8] - (cnt5[d8 * RR + 0] + cnt5[d8 * RR + 1] + cnt5[d8 * RR + 2]
                                   + cnt5[d8 * RR + 3] + cnt5[d8 * RR + 4])) + rk;
        unsigned int cnt = (unsigned)cnt5[d8 * RR + (e & 7)];
        epair[pos] = (cnt << 23) | (e & 0xFFFFFu);
    }
}

// ---------------- fused layer: 8-chain x8-unroll gather into LDS, then MFMA ----------------
// Phase 1: 8-lane group per node; per-dst weight LUT wlutS[row][r] = comp[r]*norm5(dst,r).
// Cached (L1) loads: the 8 lanes of a group share one 128-B hH line (R17 lesson: NT broke this).
// Phase 2: MFMA 16x16x32_f16, K=192, s_setprio(1) around the MFMA cluster.
// DO2: fused layer-2 GEMV epilogue -> xW2, h2.
template <int DO2>
__launch_bounds__(256)
__global__ void k_layer(const int2* __restrict__ rowse, const unsigned int* __restrict__ epair,
                        const float* __restrict__ norm5g, const float* __restrict__ comp,
                        const unsigned short* __restrict__ hH, const unsigned short* __restrict__ Wt,
                        const float* __restrict__ bias, unsigned short* __restrict__ outH,
                        const float* __restrict__ bases2, const float* __restrict__ comp2,
                        const float* __restrict__ root2, const float* __restrict__ bias2,
                        float* __restrict__ xW2, float* __restrict__ h2) {
    __shared__ float2 lut[8];
    __shared__ float2 wlutS[64][8];
    __shared__ _Float16 mixs[64][MPITCH];
    __shared__ float sW2[6 * HH];
    int tid = threadIdx.x;
    int wave = tid >> 6;
    int lane = tid & 63;
    if (tid < 8) {
        int r = tid < RR ? tid : 0;
        lut[tid] = make_float2(comp[r * NBB + 0], comp[r * NBB + 1]);
    }
    if (DO2) {
        for (int i2 = tid; i2 < 6 * HH; i2 += 256) {
            int c = i2 >> 6, k = i2 & 63;
            sW2[i2] = (c < RR) ? (comp2[c * NBB + 0] * bases2[k] + comp2[c * NBB + 1] * bases2[HH + k])
                               : root2[k];
        }
    }
    __syncthreads();

    int n0 = blockIdx.x * 64;
    int g  = lane >> 3;          // node subgroup 0..7
    int dq = lane & 7;           // dim octet: dims [dq*8, dq*8+8)

    // ---- phase 1: 8 nodes per wave concurrently, 8-edge batches ----
    for (int i = 0; i < 2; ++i) {
        int row = wave * 16 + i * 8 + g;
        int node = n0 + row;
        float m0[8] = {}, m1[8] = {};
        int beg = 0, end = 0;
        if (node < NN) { int2 se = rowse[node]; beg = se.x; end = se.y; }
        float nv = (dq < RR && node < NN) ? norm5g[(size_t)node * RR + dq] : 0.f;
        float2 cw = (dq < RR) ? make_float2(lut[dq].x * nv, lut[dq].y * nv)
                              : make_float2(0.f, 0.f);
        wlutS[row][dq] = cw;

        unsigned int p[8];
#pragma unroll
        for (int u = 0; u < 8; ++u) p[u] = (beg + u < end) ? epair[beg + u] : 5u;
        for (int j = beg; j < end; j += 8) {
            unsigned int q[8];
#pragma unroll
            for (int u = 0; u < 8; ++u)
                q[u] = (j + 8 + u < end) ? epair[j + 8 + u] : 5u;
            uint4 ua[8];
#pragma unroll
            for (int u = 0; u < 8; ++u)
                ua[u] = *(const uint4*)&hH[(size_t)((p[u] >> 3) & 0x1FFFFu) * HH + dq * 8];
#pragma unroll
            for (int u = 0; u < 8; ++u) {
                float2 cc = wlutS[row][p[u] & 7];
                float a0 = cc.x, a1 = cc.y;
                float2 f;
                f = __half22float2(*(__half2*)&ua[u].x);
                m0[0] += a0 * f.x; m0[1] += a0 * f.y; m1[0] += a1 * f.x; m1[1] += a1 * f.y;
                f = __half22float2(*(__half2*)&ua[u].y);
                m0[2] += a0 * f.x; m0[3] += a0 * f.y; m1[2] += a1 * f.x; m1[3] += a1 * f.y;
                f = __half22float2(*(__half2*)&ua[u].z);
                m0[4] += a0 * f.x; m0[5] += a0 * f.y; m1[4] += a1 * f.x; m1[5] += a1 * f.y;
                f = __half22float2(*(__half2*)&ua[u].w);
                m0[6] += a0 * f.x; m0[7] += a0 * f.y; m1[6] += a1 * f.x; m1[7] += a1 * f.y;
            }
#pragma unroll
            for (int u = 0; u < 8; ++u) p[u] = q[u];
        }
        __half2 a01 = __floats2half2_rn(m0[0], m0[1]);
        __half2 a23 = __floats2half2_rn(m0[2], m0[3]);
        __half2 a45 = __floats2half2_rn(m0[4], m0[5]);
        __half2 a67 = __floats2half2_rn(m0[6], m0[7]);
        *(uint4*)&mixs[row][dq * 8] =
            make_uint4(*(unsigned*)&a01, *(unsigned*)&a23, *(unsigned*)&a45, *(unsigned*)&a67);
        __half2 b01 = __floats2half2_rn(m1[0], m1[1]);
        __half2 b23 = __floats2half2_rn(m1[2], m1[3]);
        __half2 b45 = __floats2half2_rn(m1[4], m1[5]);
        __half2 b67 = __floats2half2_rn(m1[6], m1[7]);
        *(uint4*)&mixs[row][64 + dq * 8] =
            make_uint4(*(unsigned*)&b01, *(unsigned*)&b23, *(unsigned*)&b45, *(unsigned*)&b67);
    }
    // no barrier: phase 2 A-frags read only this wave's mixs rows

    // ---- phase 2: MFMA ----
    int lm = lane & 15;
    int lk = (lane >> 4) * 8;
    int rowA = wave * 16 + lm;
    int nodeA = n0 + rowA;
    int nodeClamp = nodeA < NN ? nodeA : NN - 1;

    f32x4 acc0 = {}, acc1 = {}, acc2 = {}, acc3 = {};
    __builtin_amdgcn_s_setprio(1);
#pragma unroll
    for (int ks = 0; ks < 6; ++ks) {
        f16x8 a;
        if (ks < 4) a = *(const f16x8*)&mixs[rowA][ks * 32 + lk];
        else        a = *(const f16x8*)&hH[(size_t)nodeClamp * HH + (ks - 4) * 32 + lk];
        f16x8 b0 = *(const f16x8*)&Wt[(size_t)(0 * 16 + lm) * 192 + ks * 32 + lk];
        f16x8 b1 = *(const f16x8*)&Wt[(size_t)(1 * 16 + lm) * 192 + ks * 32 + lk];
        f16x8 b2 = *(const f16x8*)&Wt[(size_t)(2 * 16 + lm) * 192 + ks * 32 + lk];
        f16x8 b3 = *(const f16x8*)&Wt[(size_t)(3 * 16 + lm) * 192 + ks * 32 + lk];
        acc0 = __builtin_amdgcn_mfma_f32_16x16x32_f16(a, b0, acc0, 0, 0, 0);
        acc1 = __builtin_amdgcn_mfma_f32_16x16x32_f16(a, b1, acc1, 0, 0, 0);
        acc2 = __builtin_amdgcn_mfma_f32_16x16x32_f16(a, b2, acc2, 0, 0, 0);
        acc3 = __builtin_amdgcn_mfma_f32_16x16x32_f16(a, b3, acc3, 0, 0, 0);
    }
    __builtin_amdgcn_s_setprio(0);

    float bv0 = bias[0 * 16 + lm];
    float bv1 = bias[1 * 16 + lm];
    float bv2 = bias[2 * 16 + lm];
    float bv3 = bias[3 * 16 + lm];

    int nrow = n0 + wave * 16 + (lane >> 4) * 4;
#pragma unroll
    for (int j = 0; j < 4; ++j) {
        int node = nrow + j;
        float v0 = acc0[j] + bv0;
        float v1 = acc1[j] + bv1;
        float v2 = acc2[j] + bv2;
        float v3 = acc3[j] + bv3;
        if (node < NN) {
            __half h0 = __float2half_rn(v0), h1 = __float2half_rn(v1);
            __half h2v = __float2half_rn(v2), h3 = __float2half_rn(v3);
            outH[(size_t)node * HH +  0 + lm] = *(unsigned short*)&h0;
            outH[(size_t)node * HH + 16 + lm] = *(unsigned short*)&h1;
            outH[(size_t)node * HH + 32 + lm] = *(unsigned short*)&h2v;
            outH[(size_t)node * HH + 48 + lm] = *(unsigned short*)&h3;
        }
        if (DO2) {
            float p0 = v0 * sW2[0 * HH + lm] + v1 * sW2[0 * HH + 16 + lm]
                     + v2 * sW2[0 * HH + 32 + lm] + v3 * sW2[0 * HH + 48 + lm];
            float p1 = v0 * sW2[1 * HH + lm] + v1 * sW2[1 * HH + 16 + lm]
                     + v2 * sW2[1 * HH + 32 + lm] + v3 * sW2[1 * HH + 48 + lm];
            float p2 = v0 * sW2[2 * HH + lm] + v1 * sW2[2 * HH + 16 + lm]
                     + v2 * sW2[2 * HH + 32 + lm] + v3 * sW2[2 * HH + 48 + lm];
            float p3 = v0 * sW2[3 * HH + lm] + v1 * sW2[3 * HH + 16 + lm]
                     + v2 * sW2[3 * HH + 32 + lm] + v3 * sW2[3 * HH + 48 + lm];
            float p4 = v0 * sW2[4 * HH + lm] + v1 * sW2[4 * HH + 16 + lm]
                     + v2 * sW2[4 * HH + 32 + lm] + v3 * sW2[4 * HH + 48 + lm];
            float p5 = v0 * sW2[5 * HH + lm] + v1 * sW2[5 * HH + 16 + lm]
                     + v2 * sW2[5 * HH + 32 + lm] + v3 * sW2[5 * HH + 48 + lm];
#pragma unroll
            for (int off = 1; off < 16; off <<= 1) {
                p0 += __shfl_xor(p0, off); p1 += __shfl_xor(p1, off);
                p2 += __shfl_xor(p2, off); p3 += __shfl_xor(p3, off);
                p4 += __shfl_xor(p4, off); p5 += __shfl_xor(p5, off);
            }
            if (lm == 0 && node < NN) {
                xW2[(size_t)node * RR + 0] = p0;
                xW2[(size_t)node * RR + 1] = p1;
                xW2[(size_t)node * RR + 2] = p2;
                xW2[(size_t)node * RR + 3] = p3;
                xW2[(size_t)node * RR + 4] = p4;
                h2[node] = p5 + bias2[0];
            }
        }
    }
}

// ---------------- layer-2 gather (x4-unrolled MLP) + fused masked exp-sum ----------------
__global__ void k_gather2(const int2* __restrict__ rowse, const unsigned int* __restrict__ epair,
                          const float* __restrict__ xW2, float* __restrict__ h2,
                          const int* __restrict__ absorbed, float* __restrict__ denom) {
    __shared__ float sdata[256];
    int tid = threadIdx.x;
    int n = blockIdx.x * blockDim.x + tid;
    float local = 0.f;
    if (n < NN) {
        int2 se = rowse[n];
        float acc = h2[n];
        for (int j = se.x; j < se.y; j += 4) {
            unsigned int pp[4];
            float xv[4];
#pragma unroll
            for (int u = 0; u < 4; ++u)
                pp[u] = epair[(j + u < se.y) ? j + u : se.x];
#pragma unroll
            for (int u = 0; u < 4; ++u)
                xv[u] = xW2[(size_t)((pp[u] >> 3) & 0x1FFFFu) * RR + (pp[u] & 7)];
#pragma unroll
            for (int u = 0; u < 4; ++u) {
                if (j + u < se.y) {
                    int c = pp[u] >> 23;
                    acc += (1.0f / (float)(c > 1 ? c : 1)) * xv[u];
                }
            }
        }
        h2[n] = acc;
        if (!absorbed[n]) local = expf(acc);
    }
    sdata[tid] = local;
    __syncthreads();
    for (int s = 128; s > 0; s >>= 1) {
        if (tid < s) sdata[tid] += sdata[tid + s];
        __syncthreads();
    }
    if (tid == 0) atomicAdd(denom, sdata[0]);
}

// ---------------- final normalize ----------------
__global__ void k_final(const float* __restrict__ h2, const int* __restrict__ absorbed,
                        const float* __restrict__ denom, float* __restrict__ out) {
    int n = blockIdx.x * blockDim.x + threadIdx.x;
    if (n >= NN) return;
    out[n] = absorbed[n] ? 0.f : expf(h2[n]) / denom[0];
}

extern "C" void kernel_launch(void* const* d_in, const int* in_sizes, int n_in,
                              void* d_out, int out_size, void* d_ws, size_t ws_size,
                              hipStream_t stream) {
    const int* x     = (const int*)d_in[0];
    const int* ei    = (const int*)d_in[1];
    const int* et    = (const int*)d_in[2];
    const int* order = (const int*)d_in[3];
    const float* emb = (const float*)d_in[4];
    const float* bases[3] = {(const float*)d_in[5], (const float*)d_in[9],  (const float*)d_in[13]};
    const float* comp[3]  = {(const float*)d_in[6], (const float*)d_in[10], (const float*)d_in[14]};
    const float* root[3]  = {(const float*)d_in[7], (const float*)d_in[11], (const float*)d_in[15]};
    const float* bias[3]  = {(const float*)d_in[8], (const float*)d_in[12], (const float*)d_in[16]};
    const int* srcp = ei;
    const int* dstp = ei + NE;

    char* w = (char*)d_ws;
    size_t off = 0;
    auto alloc = [&](size_t bytes) -> void* {
        void* p = w + off;
        off = (off + bytes + 255) & ~(size_t)255;
        return p;
    };
    unsigned short* hHa = (unsigned short*)alloc((size_t)NN * HH * 2);
    unsigned short* hHb = (unsigned short*)alloc((size_t)NN * HH * 2);
    float* xW2      = (float*)alloc((size_t)NN * RR * 4);
    float* h2       = (float*)alloc((size_t)NN * 4);
    int*   absorbed = (int*)alloc((size_t)NN * 4);
    int2*  rowse    = (int2*)alloc((size_t)NN * 8);
    float* norm5g   = (float*)alloc((size_t)NN * RR * 4);
    int*   bcur     = (int*)alloc((size_t)(NBK + 64) * 4);   // bcur[0..NBK) + denom at tail
    float* denom    = (float*)(bcur + NBK);
    unsigned int* ebuf  = (unsigned int*)alloc((size_t)NBK * BSLOT * 4);
    unsigned int* epair = (unsigned int*)alloc((size_t)NBK * BSLOT * 4);
    unsigned short* Wt  = (unsigned short*)alloc((size_t)NWT * 2);

    // one memset zeroes bcur + denom (adjacent)
    hipMemsetAsync(bcur, 0, (size_t)(NBK + 1) * 4, stream);

    // K1: init hH/absorbed + Wt + bucket place (independent roles, one kernel)
    k_init_place<<<NIB + NWB + 256, 256, 0, stream>>>(x, (const float4*)emb, hHa, absorbed,
                                                      bases[0], root[0], bases[1], root[1], Wt,
                                                      srcp, dstp, et, bcur, ebuf);

    // K2: bucket sort + PE add (tail blocks)
    k_bsort<<<NBK + PEBLK, 256, 0, stream>>>(ebuf, bcur, epair, rowse, norm5g,
                                             order, hHa, absorbed);

    int glayer = (NN + 63) / 64;

    // layer 0: hHa -> hHb
    k_layer<0><<<glayer, 256, 0, stream>>>(rowse, epair, norm5g, comp[0], hHa, Wt, bias[0], hHb,
                                           nullptr, nullptr, nullptr, nullptr, nullptr, nullptr);
    // layer 1: hHb -> hHa, with fused layer-2 GEMV epilogue -> xW2, h2
    k_layer<1><<<glayer, 256, 0, stream>>>(rowse, epair, norm5g, comp[1], hHb,
                                           Wt + (size_t)64 * 192, bias[1], hHa,
                                           bases[2], comp[2], root[2], bias[2], xW2, h2);

    // layer 2 aggregation + masked exp-sum, then normalize
    k_gather2<<<(NN + 255) / 256, 256, 0, stream>>>(rowse, epair, xW2, h2, absorbed, denom);
    k_final<<<(NN + 255) / 256, 256, 0, stream>>>(h2, absorbed, denom, (float*)d_out);
}

// Round 21
// 162.795 us; speedup vs baseline: 1.0463x; 1.0463x over previous
//
#include <hip/hip_runtime.h>
#include <hip/hip_fp16.h>
#include <math.h>

#define NN 100000
#define NE 1600000
#define RR 5
#define HH 64
#define KK 10000
#define NBB 2
#define NBK 391            // dst buckets of 256 nodes
#define EPB 6250           // edges per block in bucket pass (256 blocks)
#define BSLOT 4608         // padded slots per bucket (mean 4096 + 8 sigma)
#define MPITCH 136         // LDS mix row pitch in halves
#define NWT (2 * 64 * 192) // Wt element count
#define PEBLK ((KK * 16 + 255) / 256)   // pe blocks appended to bplace grid

typedef _Float16 f16x8 __attribute__((ext_vector_type(8)));
typedef float f32x4 __attribute__((ext_vector_type(4)));

// ---------------- h init: hH[n] = fp16(emb[x[n]]) + zero scratch + Wt build (grid tail) ----------------
__global__ void k_init_h(const int* __restrict__ x, const float4* __restrict__ emb4,
                         unsigned short* __restrict__ hH, int* __restrict__ bcur,
                         int* __restrict__ absorbed, float* __restrict__ denom,
                         const float* __restrict__ b0, const float* __restrict__ r0,
                         const float* __restrict__ b1, const float* __restrict__ r1,
                         unsigned short* __restrict__ Wt) {
    int idx = blockIdx.x * blockDim.x + threadIdx.x;
    if (idx < NN * 16) {
        int n = idx >> 4;
        int q = idx & 15;
        float4 v = emb4[x[n] * 16 + q];
        __half2 lo = __floats2half2_rn(v.x, v.y);
        __half2 hi = __floats2half2_rn(v.z, v.w);
        *(uint2*)&hH[(size_t)n * HH + q * 4] = make_uint2(*(unsigned*)&lo, *(unsigned*)&hi);
        if (idx < NBK) bcur[idx] = 0;
        if (idx == NBK) denom[0] = 0.f;
        if (idx < NN) absorbed[idx] = 0;
    } else if (idx < NN * 16 + NWT) {
        int widx = idx - NN * 16;
        int layer = widx / (64 * 192);
        int rem = widx - layer * 64 * 192;
        int o = rem / 192, k = rem - o * 192;
        const float* bases = layer ? b1 : b0;
        const float* root  = layer ? r1 : r0;
        float w = (k < 64)  ? bases[(size_t)k * HH + o]
                : (k < 128) ? bases[(size_t)HH * HH + (size_t)(k - 64) * HH + o]
                            : root[(size_t)(k - 128) * HH + o];
        __half hv = __float2half_rn(w);
        Wt[widx] = *(unsigned short*)&hv;
    }
}

// ---------------- bucket place (single-pass, LDS-staged) + PE add (tail blocks) ----------------
// ebuf entry = (dst&255)<<20 | src<<3 | rel ; bucket b occupies [b*BSLOT, b*BSLOT+cnt)
// Blocks [0,256): bplace. Blocks [256, 256+PEBLK): PE add + absorbed (both depend only on init).
__launch_bounds__(256)
__global__ void k_bplace(const int* __restrict__ src, const int* __restrict__ dst,
                         const int* __restrict__ et, int* __restrict__ bcur,
                         unsigned int* __restrict__ ebuf,
                         const int* __restrict__ order, unsigned short* __restrict__ hH,
                         int* __restrict__ absorbed) {
    __shared__ unsigned int ent[EPB];
    __shared__ unsigned short bkt[EPB];
    __shared__ int hist[NBK];
    __shared__ int lbase[NBK];
    __shared__ int lcur[NBK];
    int tid = threadIdx.x;

    if (blockIdx.x >= 256) {
        // ---- PE add + absorbed mask ----
        int idx = (blockIdx.x - 256) * 256 + tid;
        if (idx >= KK * 16) return;
        int t = idx >> 4;
        int q = idx & 15;
        int node = order[t];
        float v = (float)sin((double)(t + 1));   // exact arg reduction, matches np
        uint2 u = *(uint2*)&hH[(size_t)node * HH + q * 4];
        float2 lo = __half22float2(*(__half2*)&u.x);
        float2 hi = __half22float2(*(__half2*)&u.y);
        __half2 nlo = __floats2half2_rn(lo.x + v, lo.y + v);
        __half2 nhi = __floats2half2_rn(hi.x + v, hi.y + v);
        *(uint2*)&hH[(size_t)node * HH + q * 4] = make_uint2(*(unsigned*)&nlo, *(unsigned*)&nhi);
        if (q == 0) absorbed[node] = 1;
        return;
    }

    for (int i = tid; i < NBK; i += 256) { hist[i] = 0; lcur[i] = 0; }
    __syncthreads();
    int e0 = blockIdx.x * EPB;
    int e1 = e0 + EPB < NE ? e0 + EPB : NE;
    int cnt = e1 - e0;
    for (int i = tid; i < cnt; i += 256) {
        int e = e0 + i;
        int d = dst[e];
        int b = d >> 8;
        ent[i] = ((unsigned)(d & 255) << 20) | ((unsigned)src[e] << 3) | (unsigned)et[e];
        bkt[i] = (unsigned short)b;
        atomicAdd(&hist[b], 1);
    }
    __syncthreads();
    for (int i = tid; i < NBK; i += 256)
        if (hist[i]) lbase[i] = i * BSLOT + atomicAdd(&bcur[i], hist[i]);
    __syncthreads();
    for (int i = tid; i < cnt; i += 256) {
        int b = bkt[i];
        int r = atomicAdd(&lcur[b], 1);
        int idx = lbase[b] + r;
        if (idx < (b + 1) * BSLOT)
            ebuf[idx] = ent[i];
    }
}

// ---------------- bucket sort: per-dst grouping + cnt -> epair(4B), rowse, norm5g ----------------
// epair entry = cnt<<23 | src<<3 | rel
__launch_bounds__(256)
__global__ void k_bsort(const unsigned int* __restrict__ ebuf, const int* __restrict__ bcur,
                        unsigned int* __restrict__ epair, int2* __restrict__ rowse,
                        float* __restrict__ norm5g) {
    __shared__ unsigned int el[BSLOT];
    __shared__ int cnt5[256 * RR];
    __shared__ int dcur[256];
    __shared__ int s[256];
    int tid = threadIdx.x;
    int b = blockIdx.x;
    int base = b * BSLOT;
    int sz = bcur[b];
    if (sz > BSLOT) sz = BSLOT;

    for (int i = tid; i < sz; i += 256) el[i] = ebuf[base + i];
    for (int i = tid; i < 256 * RR; i += 256) cnt5[i] = 0;
    __syncthreads();
    for (int i = tid; i < sz; i += 256) {
        unsigned int e = el[i];
        atomicAdd(&cnt5[(e >> 20) * RR + (e & 7)], 1);
    }
    __syncthreads();
    int deg = 0;
#pragma unroll
    for (int r = 0; r < RR; r++) deg += cnt5[tid * RR + r];
    s[tid] = deg;
    dcur[tid] = 0;
    __syncthreads();
#pragma unroll
    for (int off = 1; off < 256; off <<= 1) {
        int t = (tid >= off) ? s[tid - off] : 0;
        __syncthreads();
        s[tid] += t;
        __syncthreads();
    }
    int rs = s[tid] - deg;      // exclusive within bucket
    int d = b * 256 + tid;
    if (d < NN) {
        rowse[d] = make_int2(base + rs, base + rs + deg);
#pragma unroll
        for (int r = 0; r < RR; r++) {
            int c = cnt5[tid * RR + r];
            norm5g[(size_t)d * RR + r] = 1.0f / (float)(c > 1 ? c : 1);
        }
    }
    __syncthreads();
    for (int i = tid; i < sz; i += 256) {
        unsigned int e = el[i];
        int d8 = e >> 20;
        int rk = atomicAdd(&dcur[d8], 1);
        int pos = base + (s[d8] - (cnt5[d8 * RR + 0] + cnt5[d8 * RR + 1] + cnt5[d8 * RR + 2]
                                   + cnt5[d8 * RR + 3] + cnt5[d8 * RR + 4])) + rk;
        unsigned int cnt = (unsigned)cnt5[d8 * RR + (e & 7)];
        epair[pos] = (cnt << 23) | (e & 0xFFFFFu);
    }
}

// ---------------- fused layer: 8-chain x8-unroll gather into LDS, then MFMA ----------------
// Phase 1: 8-lane group per node; per-dst weight LUT wlutS[row][r] = comp[r]*norm5(dst,r).
// Cached (L1) loads: the 8 lanes of a group share one 128-B hH line (R17 lesson: NT broke this).
// Phase 2: MFMA 16x16x32_f16, K=192, s_setprio(1) around the MFMA cluster.
// DO2: fused layer-2 GEMV epilogue -> xW2, h2.
template <int DO2>
__launch_bounds__(256)
__global__ void k_layer(const int2* __restrict__ rowse, const unsigned int* __restrict__ epair,
                        const float* __restrict__ norm5g, const float* __restrict__ comp,
                        const unsigned short* __restrict__ hH, const unsigned short* __restrict__ Wt,
                        const float* __restrict__ bias, unsigned short* __restrict__ outH,
                        const float* __restrict__ bases2, const float* __restrict__ comp2,
                        const float* __restrict__ root2, const float* __restrict__ bias2,
                        float* __restrict__ xW2, float* __restrict__ h2) {
    __shared__ float2 lut[8];
    __shared__ float2 wlutS[64][8];
    __shared__ _Float16 mixs[64][MPITCH];
    __shared__ float sW2[6 * HH];
    int tid = threadIdx.x;
    int wave = tid >> 6;
    int lane = tid & 63;
    if (tid < 8) {
        int r = tid < RR ? tid : 0;
        lut[tid] = make_float2(comp[r * NBB + 0], comp[r * NBB + 1]);
    }
    if (DO2) {
        for (int i2 = tid; i2 < 6 * HH; i2 += 256) {
            int c = i2 >> 6, k = i2 & 63;
            sW2[i2] = (c < RR) ? (comp2[c * NBB + 0] * bases2[k] + comp2[c * NBB + 1] * bases2[HH + k])
                               : root2[k];
        }
    }
    __syncthreads();

    int n0 = blockIdx.x * 64;
    int g  = lane >> 3;          // node subgroup 0..7
    int dq = lane & 7;           // dim octet: dims [dq*8, dq*8+8)

    // ---- phase 1: 8 nodes per wave concurrently, 8-edge batches ----
    for (int i = 0; i < 2; ++i) {
        int row = wave * 16 + i * 8 + g;
        int node = n0 + row;
        float m0[8] = {}, m1[8] = {};
        int beg = 0, end = 0;
        if (node < NN) { int2 se = rowse[node]; beg = se.x; end = se.y; }
        float nv = (dq < RR && node < NN) ? norm5g[(size_t)node * RR + dq] : 0.f;
        float2 cw = (dq < RR) ? make_float2(lut[dq].x * nv, lut[dq].y * nv)
                              : make_float2(0.f, 0.f);
        wlutS[row][dq] = cw;

        unsigned int p[8];
#pragma unroll
        for (int u = 0; u < 8; ++u) p[u] = (beg + u < end) ? epair[beg + u] : 5u;
        for (int j = beg; j < end; j += 8) {
            unsigned int q[8];
#pragma unroll
            for (int u = 0; u < 8; ++u)
                q[u] = (j + 8 + u < end) ? epair[j + 8 + u] : 5u;
            uint4 ua[8];
#pragma unroll
            for (int u = 0; u < 8; ++u)
                ua[u] = *(const uint4*)&hH[(size_t)((p[u] >> 3) & 0x1FFFFu) * HH + dq * 8];
#pragma unroll
            for (int u = 0; u < 8; ++u) {
                float2 cc = wlutS[row][p[u] & 7];
                float a0 = cc.x, a1 = cc.y;
                float2 f;
                f = __half22float2(*(__half2*)&ua[u].x);
                m0[0] += a0 * f.x; m0[1] += a0 * f.y; m1[0] += a1 * f.x; m1[1] += a1 * f.y;
                f = __half22float2(*(__half2*)&ua[u].y);
                m0[2] += a0 * f.x; m0[3] += a0 * f.y; m1[2] += a1 * f.x; m1[3] += a1 * f.y;
                f = __half22float2(*(__half2*)&ua[u].z);
                m0[4] += a0 * f.x; m0[5] += a0 * f.y; m1[4] += a1 * f.x; m1[5] += a1 * f.y;
                f = __half22float2(*(__half2*)&ua[u].w);
                m0[6] += a0 * f.x; m0[7] += a0 * f.y; m1[6] += a1 * f.x; m1[7] += a1 * f.y;
            }
#pragma unroll
            for (int u = 0; u < 8; ++u) p[u] = q[u];
        }
        __half2 a01 = __floats2half2_rn(m0[0], m0[1]);
        __half2 a23 = __floats2half2_rn(m0[2], m0[3]);
        __half2 a45 = __floats2half2_rn(m0[4], m0[5]);
        __half2 a67 = __floats2half2_rn(m0[6], m0[7]);
        *(uint4*)&mixs[row][dq * 8] =
            make_uint4(*(unsigned*)&a01, *(unsigned*)&a23, *(unsigned*)&a45, *(unsigned*)&a67);
        __half2 b01 = __floats2half2_rn(m1[0], m1[1]);
        __half2 b23 = __floats2half2_rn(m1[2], m1[3]);
        __half2 b45 = __floats2half2_rn(m1[4], m1[5]);
        __half2 b67 = __floats2half2_rn(m1[6], m1[7]);
        *(uint4*)&mixs[row][64 + dq * 8] =
            make_uint4(*(unsigned*)&b01, *(unsigned*)&b23, *(unsigned*)&b45, *(unsigned*)&b67);
    }
    // no barrier: phase 2 A-frags read only this wave's mixs rows

    // ---- phase 2: MFMA ----
    int lm = lane & 15;
    int lk = (lane >> 4) * 8;
    int rowA = wave * 16 + lm;
    int nodeA = n0 + rowA;
    int nodeClamp = nodeA < NN ? nodeA : NN - 1;

    f32x4 acc0 = {}, acc1 = {}, acc2 = {}, acc3 = {};
    __builtin_amdgcn_s_setprio(1);
#pragma unroll
    for (int ks = 0; ks < 6; ++ks) {
        f16x8 a;
        if (ks < 4) a = *(const f16x8*)&mixs[rowA][ks * 32 + lk];
        else        a = *(const f16x8*)&hH[(size_t)nodeClamp * HH + (ks - 4) * 32 + lk];
        f16x8 b0 = *(const f16x8*)&Wt[(size_t)(0 * 16 + lm) * 192 + ks * 32 + lk];
        f16x8 b1 = *(const f16x8*)&Wt[(size_t)(1 * 16 + lm) * 192 + ks * 32 + lk];
        f16x8 b2 = *(const f16x8*)&Wt[(size_t)(2 * 16 + lm) * 192 + ks * 32 + lk];
        f16x8 b3 = *(const f16x8*)&Wt[(size_t)(3 * 16 + lm) * 192 + ks * 32 + lk];
        acc0 = __builtin_amdgcn_mfma_f32_16x16x32_f16(a, b0, acc0, 0, 0, 0);
        acc1 = __builtin_amdgcn_mfma_f32_16x16x32_f16(a, b1, acc1, 0, 0, 0);
        acc2 = __builtin_amdgcn_mfma_f32_16x16x32_f16(a, b2, acc2, 0, 0, 0);
        acc3 = __builtin_amdgcn_mfma_f32_16x16x32_f16(a, b3, acc3, 0, 0, 0);
    }
    __builtin_amdgcn_s_setprio(0);

    float bv0 = bias[0 * 16 + lm];
    float bv1 = bias[1 * 16 + lm];
    float bv2 = bias[2 * 16 + lm];
    float bv3 = bias[3 * 16 + lm];

    int nrow = n0 + wave * 16 + (lane >> 4) * 4;
#pragma unroll
    for (int j = 0; j < 4; ++j) {
        int node = nrow + j;
        float v0 = acc0[j] + bv0;
        float v1 = acc1[j] + bv1;
        float v2 = acc2[j] + bv2;
        float v3 = acc3[j] + bv3;
        if (node < NN) {
            __half h0 = __float2half_rn(v0), h1 = __float2half_rn(v1);
            __half h2v = __float2half_rn(v2), h3 = __float2half_rn(v3);
            outH[(size_t)node * HH +  0 + lm] = *(unsigned short*)&h0;
            outH[(size_t)node * HH + 16 + lm] = *(unsigned short*)&h1;
            outH[(size_t)node * HH + 32 + lm] = *(unsigned short*)&h2v;
            outH[(size_t)node * HH + 48 + lm] = *(unsigned short*)&h3;
        }
        if (DO2) {
            float p0 = v0 * sW2[0 * HH + lm] + v1 * sW2[0 * HH + 16 + lm]
                     + v2 * sW2[0 * HH + 32 + lm] + v3 * sW2[0 * HH + 48 + lm];
            float p1 = v0 * sW2[1 * HH + lm] + v1 * sW2[1 * HH + 16 + lm]
                     + v2 * sW2[1 * HH + 32 + lm] + v3 * sW2[1 * HH + 48 + lm];
            float p2 = v0 * sW2[2 * HH + lm] + v1 * sW2[2 * HH + 16 + lm]
                     + v2 * sW2[2 * HH + 32 + lm] + v3 * sW2[2 * HH + 48 + lm];
            float p3 = v0 * sW2[3 * HH + lm] + v1 * sW2[3 * HH + 16 + lm]
                     + v2 * sW2[3 * HH + 32 + lm] + v3 * sW2[3 * HH + 48 + lm];
            float p4 = v0 * sW2[4 * HH + lm] + v1 * sW2[4 * HH + 16 + lm]
                     + v2 * sW2[4 * HH + 32 + lm] + v3 * sW2[4 * HH + 48 + lm];
            float p5 = v0 * sW2[5 * HH + lm] + v1 * sW2[5 * HH + 16 + lm]
                     + v2 * sW2[5 * HH + 32 + lm] + v3 * sW2[5 * HH + 48 + lm];
#pragma unroll
            for (int off = 1; off < 16; off <<= 1) {
                p0 += __shfl_xor(p0, off); p1 += __shfl_xor(p1, off);
                p2 += __shfl_xor(p2, off); p3 += __shfl_xor(p3, off);
                p4 += __shfl_xor(p4, off); p5 += __shfl_xor(p5, off);
            }
            if (lm == 0 && node < NN) {
                xW2[(size_t)node * RR + 0] = p0;
                xW2[(size_t)node * RR + 1] = p1;
                xW2[(size_t)node * RR + 2] = p2;
                xW2[(size_t)node * RR + 3] = p3;
                xW2[(size_t)node * RR + 4] = p4;
                h2[node] = p5 + bias2[0];
            }
        }
    }
}

// ---------------- layer-2 gather (x4-unrolled MLP) + fused masked exp-sum ----------------
__global__ void k_gather2(const int2* __restrict__ rowse, const unsigned int* __restrict__ epair,
                          const float* __restrict__ xW2, float* __restrict__ h2,
                          const int* __restrict__ absorbed, float* __restrict__ denom) {
    __shared__ float sdata[256];
    int tid = threadIdx.x;
    int n = blockIdx.x * blockDim.x + tid;
    float local = 0.f;
    if (n < NN) {
        int2 se = rowse[n];
        float acc = h2[n];
        for (int j = se.x; j < se.y; j += 4) {
            unsigned int pp[4];
            float xv[4];
#pragma unroll
            for (int u = 0; u < 4; ++u)
                pp[u] = epair[(j + u < se.y) ? j + u : se.x];
#pragma unroll
            for (int u = 0; u < 4; ++u)
                xv[u] = xW2[(size_t)((pp[u] >> 3) & 0x1FFFFu) * RR + (pp[u] & 7)];
#pragma unroll
            for (int u = 0; u < 4; ++u) {
                if (j + u < se.y) {
                    int c = pp[u] >> 23;
                    acc += (1.0f / (float)(c > 1 ? c : 1)) * xv[u];
                }
            }
        }
        h2[n] = acc;
        if (!absorbed[n]) local = expf(acc);
    }
    sdata[tid] = local;
    __syncthreads();
    for (int s = 128; s > 0; s >>= 1) {
        if (tid < s) sdata[tid] += sdata[tid + s];
        __syncthreads();
    }
    if (tid == 0) atomicAdd(denom, sdata[0]);
}

// ---------------- final normalize ----------------
__global__ void k_final(const float* __restrict__ h2, const int* __restrict__ absorbed,
                        const float* __restrict__ denom, float* __restrict__ out) {
    int n = blockIdx.x * blockDim.x + threadIdx.x;
    if (n >= NN) return;
    out[n] = absorbed[n] ? 0.f : expf(h2[n]) / denom[0];
}

extern "C" void kernel_launch(void* const* d_in, const int* in_sizes, int n_in,
                              void* d_out, int out_size, void* d_ws, size_t ws_size,
                              hipStream_t stream) {
    const int* x     = (const int*)d_in[0];
    const int* ei    = (const int*)d_in[1];
    const int* et    = (const int*)d_in[2];
    const int* order = (const int*)d_in[3];
    const float* emb = (const float*)d_in[4];
    const float* bases[3] = {(const float*)d_in[5], (const float*)d_in[9],  (const float*)d_in[13]};
    const float* comp[3]  = {(const float*)d_in[6], (const float*)d_in[10], (const float*)d_in[14]};
    const float* root[3]  = {(const float*)d_in[7], (const float*)d_in[11], (const float*)d_in[15]};
    const float* bias[3]  = {(const float*)d_in[8], (const float*)d_in[12], (const float*)d_in[16]};
    const int* srcp = ei;
    const int* dstp = ei + NE;

    char* w = (char*)d_ws;
    size_t off = 0;
    auto alloc = [&](size_t bytes) -> void* {
        void* p = w + off;
        off = (off + bytes + 255) & ~(size_t)255;
        return p;
    };
    unsigned short* hHa = (unsigned short*)alloc((size_t)NN * HH * 2);
    unsigned short* hHb = (unsigned short*)alloc((size_t)NN * HH * 2);
    float* xW2      = (float*)alloc((size_t)NN * RR * 4);
    float* h2       = (float*)alloc((size_t)NN * 4);
    int*   absorbed = (int*)alloc((size_t)NN * 4);
    int2*  rowse    = (int2*)alloc((size_t)NN * 8);
    float* norm5g   = (float*)alloc((size_t)NN * RR * 4);
    int*   bcur     = (int*)alloc((size_t)NBK * 4);
    unsigned int* ebuf  = (unsigned int*)alloc((size_t)NBK * BSLOT * 4);
    unsigned int* epair = (unsigned int*)alloc((size_t)NBK * BSLOT * 4);
    unsigned short* Wt  = (unsigned short*)alloc((size_t)NWT * 2);
    float* denom    = (float*)alloc(256);

    // init (also zeroes bcur/absorbed/denom; grid tail builds Wt)
    k_init_h<<<(NN * 16 + NWT + 255) / 256, 256, 0, stream>>>(x, (const float4*)emb, hHa,
                                                              bcur, absorbed, denom,
                                                              bases[0], root[0], bases[1], root[1], Wt);

    // bucket place (single-pass LDS-staged) + PE add in tail blocks
    k_bplace<<<256 + PEBLK, 256, 0, stream>>>(srcp, dstp, et, bcur, ebuf, order, hHa, absorbed);
    k_bsort<<<NBK, 256, 0, stream>>>(ebuf, bcur, epair, rowse, norm5g);

    int glayer = (NN + 63) / 64;

    // layer 0: hHa -> hHb
    k_layer<0><<<glayer, 256, 0, stream>>>(rowse, epair, norm5g, comp[0], hHa, Wt, bias[0], hHb,
                                           nullptr, nullptr, nullptr, nullptr, nullptr, nullptr);
    // layer 1: hHb -> hHa, with fused layer-2 GEMV epilogue -> xW2, h2
    k_layer<1><<<glayer, 256, 0, stream>>>(rowse, epair, norm5g, comp[1], hHb,
                                           Wt + (size_t)64 * 192, bias[1], hHa,
                                           bases[2], comp[2], root[2], bias[2], xW2, h2);

    // layer 2 aggregation + masked exp-sum, then normalize
    k_gather2<<<(NN + 255) / 256, 256, 0, stream>>>(rowse, epair, xW2, h2, absorbed, denom);
    k_final<<<(NN + 255) / 256, 256, 0, stream>>>(h2, absorbed, denom, (float*)d_out);
}